// Round 7
// baseline (17100.394 us; speedup 1.0000x reference)
//
#include <hip/hip_runtime.h>
#include <math.h>

#define Nn 131072
#define Ee 524288

typedef __attribute__((ext_vector_type(8))) short short8;
typedef __attribute__((ext_vector_type(4))) float f32x4;
typedef unsigned short ushort_t;
typedef unsigned int uint32;

__device__ __forceinline__ f32x4 mfma16(short8 a, short8 b, f32x4 c) {
    return __builtin_amdgcn_mfma_f32_16x16x32_bf16(a, b, c, 0, 0, 0);
}

__device__ __forceinline__ uint32 rne_bf16(float x) {
    uint32 u = __float_as_uint(x);
    return (u + 0x7FFFu + ((u >> 16) & 1u)) >> 16;
}

// fp32 -> 3 bf16 limbs (hi, mid, lo); hi+mid+lo ~= x to ~2^-27 rel.
__device__ __forceinline__ void split3(float x, uint32& h, uint32& m, uint32& l) {
    h = rne_bf16(x);
    float hf = __uint_as_float(h << 16);
    float r1 = x - hf;
    m = rne_bf16(r1);
    float mf = __uint_as_float(m << 16);
    float r2 = r1 - mf;
    l = rne_bf16(r2);
}

__device__ __forceinline__ float recon3(ushort_t a, ushort_t b, ushort_t c) {
    return __uint_as_float((uint32)a << 16) + __uint_as_float((uint32)b << 16) +
           __uint_as_float((uint32)c << 16);
}

// Act limb-plane row layout (ushort, 240/row, 480 B):
//   [0,100)  msg limb   [100,112) zeros   [112,212) h limb   [212,240) zeros
#define ROWS 240
#define HOFF 112

// ---------------------------------------------------------------- diag / zero
__global__ void diag_kernel(float* out, float val) {
    int n = blockIdx.x * 256 + threadIdx.x;
    if (n < Nn) out[n] = (n == 0) ? val : 0.f;
}
__global__ void zero_ints(int* p, int n) {
    int i = blockIdx.x * 256 + threadIdx.x;
    if (i < n) p[i] = 0;
}
// zero the pad columns of all three limb planes (ws is poisoned every launch)
__global__ void zero_pads(ushort_t* L0, ushort_t* L1, ushort_t* L2) {
    int gid = blockIdx.x * 256 + threadIdx.x;     // N*40
    int n = gid / 40, p = gid - n * 40;
    int off = (p < 12) ? (100 + p) : (212 + (p - 12));
    size_t idx = (size_t)n * ROWS + off;
    L0[idx] = 0; L1[idx] = 0; L2[idx] = 0;
}

// ---------------------------------------------------------------- CSR build
__global__ void hist_kernel(const int* __restrict__ er, const int* __restrict__ ec,
                            int* __restrict__ cnt_f, int* __restrict__ cnt_b) {
    int e = blockIdx.x * 256 + threadIdx.x;
    atomicAdd(&cnt_f[er[e]], 1);
    atomicAdd(&cnt_b[ec[e]], 1);
}

__global__ __launch_bounds__(1024) void scan_kernel(const int* __restrict__ cnt,
                                                    int* __restrict__ ptr, int n) {
    __shared__ int sums[1024];
    int t = threadIdx.x;
    int chunk = n >> 10;
    int base = t * chunk;
    int s = 0;
    for (int i = 0; i < chunk; i++) s += cnt[base + i];
    sums[t] = s;
    __syncthreads();
    for (int off = 1; off < 1024; off <<= 1) {
        int v = (t >= off) ? sums[t - off] : 0;
        __syncthreads();
        sums[t] += v;
        __syncthreads();
    }
    int run = (t == 0) ? 0 : sums[t - 1];
    for (int i = 0; i < chunk; i++) { ptr[base + i] = run; run += cnt[base + i]; }
    if (t == 1023) ptr[n] = run;
}

// fill advances ptr in place; afterwards start(r) = (r ? ptr[r-1] : 0), end(r) = ptr[r]
__global__ void fill_kernel(const int* __restrict__ er, const int* __restrict__ ec,
                            int* __restrict__ ptr_f, int* __restrict__ ptr_b,
                            int* __restrict__ src_f, int* __restrict__ src_b) {
    int e = blockIdx.x * 256 + threadIdx.x;
    int r = er[e], c = ec[e];
    int p = atomicAdd(&ptr_f[r], 1); src_f[p] = c;
    int q = atomicAdd(&ptr_b[c], 1); src_b[q] = r;
}

// ---------------------------------------------------------------- weight prep
// GRU: Wt[c=4d+g][k], c<448 (28 tiles); k<100: Wih, 112<=k<212: Whh, else 0.
__global__ void prep_gru_w(const float* __restrict__ Wih, const float* __restrict__ Whh,
                           const float* __restrict__ bih, const float* __restrict__ bhh,
                           ushort_t* __restrict__ W0, ushort_t* __restrict__ W1,
                           ushort_t* __restrict__ W2, float* __restrict__ bg) {
    int gid = blockIdx.x * 256 + threadIdx.x;
    if (gid >= 448 * 224) return;
    int c = gid / 224, k = gid - c * 224;
    int d = c >> 2, g = c & 3;
    float w = 0.f;
    if (d < 100) {
        if (k < 100) {
            if (g == 0)      w = Wih[d * 100 + k];
            else if (g == 1) w = Wih[(100 + d) * 100 + k];
            else if (g == 2) w = Wih[(200 + d) * 100 + k];
        } else if (k >= HOFF && k < HOFF + 100) {
            int kk = k - HOFF;
            if (g == 0)      w = Whh[d * 100 + kk];
            else if (g == 1) w = Whh[(100 + d) * 100 + kk];
            else if (g == 3) w = Whh[(200 + d) * 100 + kk];
        }
    }
    uint32 h, m, l; split3(w, h, m, l);
    W0[gid] = (ushort_t)h; W1[gid] = (ushort_t)m; W2[gid] = (ushort_t)l;
    if (k == 0) {
        float b = 0.f;
        if (d < 100) {
            if (g == 0)      b = bih[d] + bhh[d];
            else if (g == 1) b = bih[100 + d] + bhh[100 + d];
            else if (g == 2) b = bih[200 + d];
            else             b = bhh[200 + d];
        }
        bg[c] = b;
    }
}

// msg MLP: W1t[c<64][k<128] (c=hidden col, k=h dim), W2t[c<112][k<64]
__global__ void prep_msg_w(const float* __restrict__ W1, const float* __restrict__ b1,
                           const float* __restrict__ W2, const float* __restrict__ b2,
                           ushort_t* __restrict__ A0, ushort_t* __restrict__ A1,
                           ushort_t* __restrict__ A2, float* __restrict__ b1p,
                           ushort_t* __restrict__ B0, ushort_t* __restrict__ B1,
                           ushort_t* __restrict__ B2, float* __restrict__ b2p) {
    int gid = blockIdx.x * 256 + threadIdx.x;
    if (gid < 8192) {
        int c = gid >> 7, k = gid & 127;
        float w = (c < 50 && k < 100) ? W1[k * 50 + c] : 0.f;
        uint32 h, m, l; split3(w, h, m, l);
        A0[gid] = (ushort_t)h; A1[gid] = (ushort_t)m; A2[gid] = (ushort_t)l;
        if (k == 0) b1p[c] = (c < 50) ? b1[c] : 0.f;
    } else if (gid < 8192 + 7168) {
        int t = gid - 8192;
        int c = t >> 6, k = t & 63;
        float w = (c < 100 && k < 50) ? W2[k * 100 + c] : 0.f;
        uint32 h, m, l; split3(w, h, m, l);
        B0[t] = (ushort_t)h; B1[t] = (ushort_t)m; B2[t] = (ushort_t)l;
        if (k == 0) b2p[c] = (c < 100) ? b2[c] : 0.f;
    }
}

// ---------------------------------------------------------------- init h
__global__ void init_h_kernel(const float* __restrict__ feat, const float* __restrict__ W,
                              const float* __restrict__ b,
                              ushort_t* __restrict__ L0, ushort_t* __restrict__ L1,
                              ushort_t* __restrict__ L2) {
    int gid = blockIdx.x * 256 + threadIdx.x;   // N*100
    int n = gid / 100, d = gid - n * 100;
    float acc = b[d];
#pragma unroll
    for (int k = 0; k < 4; k++) acc += feat[n * 4 + k] * W[k * 100 + d];
    uint32 h, m, l; split3(acc, h, m, l);
    size_t idx = (size_t)n * ROWS + HOFF + d;
    L0[idx] = (ushort_t)h; L1[idx] = (ushort_t)m; L2[idx] = (ushort_t)l;
}

// ---------------------------------------------------------------- msg MLP (MFMA)
// fm = relu(h @ W1 + b1) @ W2 + b2 ; h read directly from limb planes.
__global__ __launch_bounds__(256, 2) void msg_mfma(
    const ushort_t* __restrict__ L0, const ushort_t* __restrict__ L1,
    const ushort_t* __restrict__ L2,
    const ushort_t* __restrict__ A0, const ushort_t* __restrict__ A1,
    const ushort_t* __restrict__ A2, const float* __restrict__ b1p,
    const ushort_t* __restrict__ B0, const ushort_t* __restrict__ B1,
    const ushort_t* __restrict__ B2, const float* __restrict__ b2p,
    float* __restrict__ fm) {
    __shared__ ushort_t C1[3][64][72];
    const int tid = threadIdx.x;
    const int u = tid >> 6;          // wave = node tile
    const int lane = tid & 63;
    const int m = lane & 15, q = lane >> 4;
    const int n0 = blockIdx.x * 64;
    const int n = n0 + u * 16 + m;

    f32x4 z = {0.f, 0.f, 0.f, 0.f};
    f32x4 a1[4] = {z, z, z, z};

    for (int kc = 0; kc < 4; kc++) {
        size_t base = (size_t)n * ROWS + HOFF + kc * 32 + q * 8;
        short8 f0 = *(const short8*)(L0 + base);
        short8 f1 = *(const short8*)(L1 + base);
        short8 f2 = *(const short8*)(L2 + base);
#pragma unroll
        for (int t = 0; t < 4; t++) {
            int off = (t * 16 + m) * 128 + kc * 32 + q * 8;
            short8 w0 = *(const short8*)(A0 + off);
            short8 w1 = *(const short8*)(A1 + off);
            short8 w2 = *(const short8*)(A2 + off);
            a1[t] = mfma16(w0, f0, a1[t]);
            a1[t] = mfma16(w0, f1, a1[t]);
            a1[t] = mfma16(w1, f0, a1[t]);
            a1[t] = mfma16(w0, f2, a1[t]);
            a1[t] = mfma16(w2, f0, a1[t]);
            a1[t] = mfma16(w1, f1, a1[t]);
        }
    }
    // epilogue 1: relu + split -> LDS
#pragma unroll
    for (int t = 0; t < 4; t++) {
        int c0 = t * 16 + 4 * q;
        float4 bb = *(const float4*)&b1p[c0];
        float v0 = fmaxf(a1[t][0] + bb.x, 0.f);
        float v1 = fmaxf(a1[t][1] + bb.y, 0.f);
        float v2 = fmaxf(a1[t][2] + bb.z, 0.f);
        float v3 = fmaxf(a1[t][3] + bb.w, 0.f);
        uint32 h0, m0, l0, h1, m1, l1, h2, m2, l2, h3, m3, l3;
        split3(v0, h0, m0, l0); split3(v1, h1, m1, l1);
        split3(v2, h2, m2, l2); split3(v3, h3, m3, l3);
        int nl = u * 16 + m;
        *(uint2*)&C1[0][nl][c0] = make_uint2(h0 | (h1 << 16), h2 | (h3 << 16));
        *(uint2*)&C1[1][nl][c0] = make_uint2(m0 | (m1 << 16), m2 | (m3 << 16));
        *(uint2*)&C1[2][nl][c0] = make_uint2(l0 | (l1 << 16), l2 | (l3 << 16));
    }
    __syncthreads();

    f32x4 a2[7] = {z, z, z, z, z, z, z};
    for (int kc = 0; kc < 2; kc++) {
        int nl = u * 16 + m;
        short8 c0f = *(const short8*)&C1[0][nl][kc * 32 + q * 8];
        short8 c1f = *(const short8*)&C1[1][nl][kc * 32 + q * 8];
        short8 c2f = *(const short8*)&C1[2][nl][kc * 32 + q * 8];
#pragma unroll
        for (int t = 0; t < 7; t++) {
            int off = (t * 16 + m) * 64 + kc * 32 + q * 8;
            short8 w0 = *(const short8*)(B0 + off);
            short8 w1 = *(const short8*)(B1 + off);
            short8 w2 = *(const short8*)(B2 + off);
            a2[t] = mfma16(w0, c0f, a2[t]);
            a2[t] = mfma16(w0, c1f, a2[t]);
            a2[t] = mfma16(w1, c0f, a2[t]);
            a2[t] = mfma16(w0, c2f, a2[t]);
            a2[t] = mfma16(w2, c0f, a2[t]);
            a2[t] = mfma16(w1, c1f, a2[t]);
        }
    }
#pragma unroll
    for (int t = 0; t < 7; t++) {
        int c0 = t * 16 + 4 * q;
        if (c0 < 100) {
            float4 bb = *(const float4*)&b2p[c0];
            float4 o;
            o.x = a2[t][0] + bb.x; o.y = a2[t][1] + bb.y;
            o.z = a2[t][2] + bb.z; o.w = a2[t][3] + bb.w;
            *(float4*)&fm[(size_t)n * 100 + c0] = o;
        }
    }
}

// ---------------------------------------------------------------- gather (CSR)
// sum in fp32, split once, write msg limbs
__global__ void gather4(const float* __restrict__ fm, const int* __restrict__ ptr,
                        const int* __restrict__ idx,
                        ushort_t* __restrict__ L0, ushort_t* __restrict__ L1,
                        ushort_t* __restrict__ L2) {
    int gid = blockIdx.x * 256 + threadIdx.x;   // N*25
    int n = gid / 25, qq = (gid - n * 25) * 4;
    int s = (n == 0) ? 0 : ptr[n - 1];
    int e = ptr[n];
    float4 acc = {0.f, 0.f, 0.f, 0.f};
    for (int i = s; i < e; i++) {
        float4 v = *(const float4*)&fm[(size_t)idx[i] * 100 + qq];
        acc.x += v.x; acc.y += v.y; acc.z += v.z; acc.w += v.w;
    }
    uint32 h0, m0, l0, h1, m1, l1, h2, m2, l2, h3, m3, l3;
    split3(acc.x, h0, m0, l0); split3(acc.y, h1, m1, l1);
    split3(acc.z, h2, m2, l2); split3(acc.w, h3, m3, l3);
    size_t base = (size_t)n * ROWS + qq;
    *(uint2*)&L0[base] = make_uint2(h0 | (h1 << 16), h2 | (h3 << 16));
    *(uint2*)&L1[base] = make_uint2(m0 | (m1 << 16), m2 | (m3 << 16));
    *(uint2*)&L2[base] = make_uint2(l0 | (l1 << 16), l2 | (l3 << 16));
}

// ---------------------------------------------------------------- GRU (MFMA) v5
// 64-row blocks, 28 col-tiles, 7 tiles/wave (ct = 4t+wave). No LDS. Activations
// read as pre-split limb fragments (zero split VALU in the k-loop). Product-major
// passes: MFMA dependency distance 28. One barrier before in-place h update.
__global__ __launch_bounds__(256, 2) void gru_mfma(
    ushort_t* __restrict__ L0, ushort_t* __restrict__ L1, ushort_t* __restrict__ L2,
    const ushort_t* __restrict__ W0, const ushort_t* __restrict__ W1,
    const ushort_t* __restrict__ W2, const float* __restrict__ bg) {
    const int tid = threadIdx.x;
    const int wave = tid >> 6;
    const int lane = tid & 63;
    const int m = lane & 15, q = lane >> 4;
    const int n0 = blockIdx.x * 64;

    f32x4 z = {0.f, 0.f, 0.f, 0.f};
    f32x4 acc[7][4];
#pragma unroll
    for (int t = 0; t < 7; t++)
#pragma unroll
        for (int rf = 0; rf < 4; rf++) acc[t][rf] = z;

    int woff[7];
#pragma unroll
    for (int t = 0; t < 7; t++)
        woff[t] = ((t * 4 + wave) * 16 + m) * 224 + q * 8;

    const size_t arow = (size_t)(n0 + m) * ROWS + q * 8;

#define GPASS(Wreg, Fr)                                          \
    _Pragma("unroll")                                            \
    for (int t = 0; t < 7; t++) {                                \
        _Pragma("unroll")                                        \
        for (int rf = 0; rf < 4; rf++)                           \
            acc[t][rf] = mfma16(Wreg[t], Fr[rf], acc[t][rf]);    \
    }

    for (int kc = 0; kc < 7; kc++) {
        const int ko = kc * 32;
        short8 f0[4], f1[4], f2[4];
#pragma unroll
        for (int rf = 0; rf < 4; rf++) {
            size_t b = arow + (size_t)rf * 16 * ROWS + ko;
            f0[rf] = *(const short8*)(L0 + b);
            f1[rf] = *(const short8*)(L1 + b);
            f2[rf] = *(const short8*)(L2 + b);
        }
        short8 w[7];
#pragma unroll
        for (int t = 0; t < 7; t++) w[t] = *(const short8*)(W0 + woff[t] + ko);
        GPASS(w, f0);                       // w0*f0
        GPASS(w, f1);                       // w0*f1
        GPASS(w, f2);                       // w0*f2
#pragma unroll
        for (int t = 0; t < 7; t++) w[t] = *(const short8*)(W1 + woff[t] + ko);
        GPASS(w, f0);                       // w1*f0
        GPASS(w, f1);                       // w1*f1
#pragma unroll
        for (int t = 0; t < 7; t++) w[t] = *(const short8*)(W2 + woff[t] + ko);
        GPASS(w, f0);                       // w2*f0
    }
#undef GPASS

    __syncthreads();    // all reads of h limbs complete before in-place overwrite

    // epilogue: gates, h update, re-split into limb planes
#pragma unroll
    for (int t = 0; t < 7; t++) {
        const int ct = t * 4 + wave;        // 0..27
        const int d = ct * 4 + q;           // 0..111
        if (d < 100) {
            float4 b4 = *(const float4*)&bg[ct * 16 + 4 * q];
#pragma unroll
            for (int rf = 0; rf < 4; rf++) {
                int n = n0 + rf * 16 + m;
                size_t idx = (size_t)n * ROWS + HOFF + d;
                float hold = recon3(L0[idx], L1[idx], L2[idx]);
                float rp = acc[t][rf][0] + b4.x;
                float zp = acc[t][rf][1] + b4.y;
                float np = acc[t][rf][2] + b4.z;
                float hh = acc[t][rf][3] + b4.w;
                float rr = 1.f / (1.f + __expf(-rp));
                float zz = 1.f / (1.f + __expf(-zp));
                float nw = tanhf(np + rr * hh);
                float hnew = (1.f - zz) * nw + zz * hold;
                uint32 h, mm, l; split3(hnew, h, mm, l);
                L0[idx] = (ushort_t)h; L1[idx] = (ushort_t)mm; L2[idx] = (ushort_t)l;
            }
        }
    }
}

// ---------------------------------------------------------------- classifier
__global__ __launch_bounds__(256) void classifier(
    const ushort_t* __restrict__ L0, const ushort_t* __restrict__ L1,
    const ushort_t* __restrict__ L2, const float* __restrict__ W1,
    const float* __restrict__ b1, const float* __restrict__ W2,
    const float* __restrict__ b2, float* __restrict__ out) {
    __shared__ float Wc[3000];
    __shared__ float bc[30];
    __shared__ float w2[30];
    int tid = threadIdx.x;
    for (int i = tid; i < 3000; i += 256) Wc[i] = W1[i];
    if (tid < 30) { bc[tid] = b1[tid]; w2[tid] = W2[tid]; }
    __syncthreads();
    int n = blockIdx.x * 256 + tid;
    float a[30];
#pragma unroll
    for (int j = 0; j < 30; j++) a[j] = bc[j];
    for (int k = 0; k < 100; k++) {
        size_t idx = (size_t)n * ROWS + HOFF + k;
        float hv = recon3(L0[idx], L1[idx], L2[idx]);
#pragma unroll
        for (int j = 0; j < 30; j++) a[j] = fmaf(hv, Wc[k * 30 + j], a[j]);
    }
    float s = b2[0];
#pragma unroll
    for (int j = 0; j < 30; j++) s = fmaf(fmaxf(a[j], 0.f), w2[j], s);
    out[n] = s;
}

// ---------------------------------------------------------------- launch
extern "C" void kernel_launch(void* const* d_in, const int* in_sizes, int n_in,
                              void* d_out, int out_size, void* d_ws, size_t ws_size,
                              hipStream_t stream) {
    const float* feat     = (const float*)d_in[0];
    const int*   er       = (const int*)d_in[1];
    const int*   ec       = (const int*)d_in[2];
    const float* init_W   = (const float*)d_in[3];
    const float* init_b   = (const float*)d_in[4];
    const float* fmsg_W1  = (const float*)d_in[5];
    const float* fmsg_b1  = (const float*)d_in[6];
    const float* fmsg_W2  = (const float*)d_in[7];
    const float* fmsg_b2  = (const float*)d_in[8];
    const float* bmsg_W1  = (const float*)d_in[9];
    const float* bmsg_b1  = (const float*)d_in[10];
    const float* bmsg_W2  = (const float*)d_in[11];
    const float* bmsg_b2  = (const float*)d_in[12];
    const float* fgru_Wih = (const float*)d_in[13];
    const float* fgru_Whh = (const float*)d_in[14];
    const float* fgru_bih = (const float*)d_in[15];
    const float* fgru_bhh = (const float*)d_in[16];
    const float* bgru_Wih = (const float*)d_in[17];
    const float* bgru_Whh = (const float*)d_in[18];
    const float* bgru_bih = (const float*)d_in[19];
    const float* bgru_bhh = (const float*)d_in[20];
    const float* cls_W1   = (const float*)d_in[21];
    const float* cls_b1   = (const float*)d_in[22];
    const float* cls_W2   = (const float*)d_in[23];
    const float* cls_b2   = (const float*)d_in[24];
    float* out = (float*)d_out;

    char* base = (char*)d_ws;
    size_t off = 0;
    auto alloc = [&](size_t bytes) -> void* {
        void* p = base + off;
        off += (bytes + 15) & ~(size_t)15;
        return p;
    };

    ushort_t* L0 = (ushort_t*)alloc((size_t)Nn * ROWS * 2);
    ushort_t* L1 = (ushort_t*)alloc((size_t)Nn * ROWS * 2);
    ushort_t* L2 = (ushort_t*)alloc((size_t)Nn * ROWS * 2);
    float*    fm = (float*)alloc((size_t)Nn * 100 * 4);

    ushort_t* fWg0 = (ushort_t*)alloc(448 * 224 * 2);
    ushort_t* fWg1 = (ushort_t*)alloc(448 * 224 * 2);
    ushort_t* fWg2 = (ushort_t*)alloc(448 * 224 * 2);
    ushort_t* bWg0 = (ushort_t*)alloc(448 * 224 * 2);
    ushort_t* bWg1 = (ushort_t*)alloc(448 * 224 * 2);
    ushort_t* bWg2 = (ushort_t*)alloc(448 * 224 * 2);
    ushort_t* fA0  = (ushort_t*)alloc(8192 * 2);
    ushort_t* fA1  = (ushort_t*)alloc(8192 * 2);
    ushort_t* fA2  = (ushort_t*)alloc(8192 * 2);
    ushort_t* bA0  = (ushort_t*)alloc(8192 * 2);
    ushort_t* bA1  = (ushort_t*)alloc(8192 * 2);
    ushort_t* bA2  = (ushort_t*)alloc(8192 * 2);
    ushort_t* fB0  = (ushort_t*)alloc(7168 * 2);
    ushort_t* fB1  = (ushort_t*)alloc(7168 * 2);
    ushort_t* fB2  = (ushort_t*)alloc(7168 * 2);
    ushort_t* bB0  = (ushort_t*)alloc(7168 * 2);
    ushort_t* bB1  = (ushort_t*)alloc(7168 * 2);
    ushort_t* bB2  = (ushort_t*)alloc(7168 * 2);

    float* bgf  = (float*)alloc(448 * 4);
    float* bgb  = (float*)alloc(448 * 4);
    float* b1pf = (float*)alloc(64 * 4);
    float* b1pb = (float*)alloc(64 * 4);
    float* b2pf = (float*)alloc(112 * 4);
    float* b2pb = (float*)alloc(112 * 4);

    int* ptr_f = (int*)alloc((Nn + 1) * 4);
    int* ptr_b = (int*)alloc((Nn + 1) * 4);
    int* cnt   = (int*)alloc(2 * (size_t)Nn * 4);
    int* cnt_f = cnt;
    int* cnt_b = cnt + Nn;
    int* src_f = (int*)alloc((size_t)Ee * 4);
    int* src_b = (int*)alloc((size_t)Ee * 4);

    if (ws_size < off) {
        // diagnostic: absmax will report ~ws_size
        diag_kernel<<<(Nn + 255) / 256, 256, 0, stream>>>(out, (float)ws_size);
        return;
    }

    // CSR build
    zero_ints<<<(2 * Nn + 255) / 256, 256, 0, stream>>>(cnt, 2 * Nn);
    hist_kernel<<<Ee / 256, 256, 0, stream>>>(er, ec, cnt_f, cnt_b);
    scan_kernel<<<1, 1024, 0, stream>>>(cnt_f, ptr_f, Nn);
    scan_kernel<<<1, 1024, 0, stream>>>(cnt_b, ptr_b, Nn);
    fill_kernel<<<Ee / 256, 256, 0, stream>>>(er, ec, ptr_f, ptr_b, src_f, src_b);

    // weight prep (split to 3 bf16 limbs)
    prep_gru_w<<<(448 * 224 + 255) / 256, 256, 0, stream>>>(
        fgru_Wih, fgru_Whh, fgru_bih, fgru_bhh, fWg0, fWg1, fWg2, bgf);
    prep_gru_w<<<(448 * 224 + 255) / 256, 256, 0, stream>>>(
        bgru_Wih, bgru_Whh, bgru_bih, bgru_bhh, bWg0, bWg1, bWg2, bgb);
    prep_msg_w<<<(15360 + 255) / 256, 256, 0, stream>>>(
        fmsg_W1, fmsg_b1, fmsg_W2, fmsg_b2, fA0, fA1, fA2, b1pf, fB0, fB1, fB2, b2pf);
    prep_msg_w<<<(15360 + 255) / 256, 256, 0, stream>>>(
        bmsg_W1, bmsg_b1, bmsg_W2, bmsg_b2, bA0, bA1, bA2, b1pb, bB0, bB1, bB2, b2pb);

    // activation plane pads + h init (split into limb planes)
    zero_pads<<<(Nn * 40) / 256, 256, 0, stream>>>(L0, L1, L2);
    init_h_kernel<<<(Nn * 100) / 256, 256, 0, stream>>>(feat, init_W, init_b, L0, L1, L2);

    const int gTile = Nn / 64;            // 2048 (msg, gru)
    const int gGath = Nn * 25 / 256;      // 12800

    for (int rd = 0; rd < 20; rd++) {
        msg_mfma<<<gTile, 256, 0, stream>>>(L0, L1, L2, fA0, fA1, fA2, b1pf,
                                            fB0, fB1, fB2, b2pf, fm);
        gather4<<<gGath, 256, 0, stream>>>(fm, ptr_f, src_f, L0, L1, L2);
        gru_mfma<<<gTile, 256, 0, stream>>>(L0, L1, L2, fWg0, fWg1, fWg2, bgf);

        msg_mfma<<<gTile, 256, 0, stream>>>(L0, L1, L2, bA0, bA1, bA2, b1pb,
                                            bB0, bB1, bB2, b2pb, fm);
        gather4<<<gGath, 256, 0, stream>>>(fm, ptr_b, src_b, L0, L1, L2);
        gru_mfma<<<gTile, 256, 0, stream>>>(L0, L1, L2, bWg0, bWg1, bWg2, bgb);
    }

    classifier<<<Nn / 256, 256, 0, stream>>>(L0, L1, L2, cls_W1, cls_b1,
                                             cls_W2, cls_b2, out);
}

// Round 8
// 16981.444 us; speedup vs baseline: 1.0070x; 1.0070x over previous
//
#include <hip/hip_runtime.h>
#include <math.h>

#define Nn 131072
#define Ee 524288

typedef __attribute__((ext_vector_type(8))) short short8;
typedef __attribute__((ext_vector_type(4))) float f32x4;
typedef unsigned short ushort_t;
typedef unsigned int uint32;

__device__ __forceinline__ f32x4 mfma16(short8 a, short8 b, f32x4 c) {
    return __builtin_amdgcn_mfma_f32_16x16x32_bf16(a, b, c, 0, 0, 0);
}

__device__ __forceinline__ uint32 rne_bf16(float x) {
    uint32 u = __float_as_uint(x);
    return (u + 0x7FFFu + ((u >> 16) & 1u)) >> 16;
}

// fp32 -> 3 bf16 limbs (hi, mid, lo); hi+mid+lo ~= x to ~2^-27 rel.
__device__ __forceinline__ void split3(float x, uint32& h, uint32& m, uint32& l) {
    h = rne_bf16(x);
    float hf = __uint_as_float(h << 16);
    float r1 = x - hf;
    m = rne_bf16(r1);
    float mf = __uint_as_float(m << 16);
    float r2 = r1 - mf;
    l = rne_bf16(r2);
}

__device__ __forceinline__ float recon3(ushort_t a, ushort_t b, ushort_t c) {
    return __uint_as_float((uint32)a << 16) + __uint_as_float((uint32)b << 16) +
           __uint_as_float((uint32)c << 16);
}

// Interleaved limb layout: row = 30 frags x 24 ushorts (48 B per frag:
// [hi x8][mid x8][lo x8]). k = frag*8 + j.
//   frags 0..12  : msg  (k 0..99; 100..103 zero)
//   frag  13     : zero (k 104..111)
//   frags 14..26 : h    (k 112..211; 212..215 zero)
//   frags 27..29 : zero
#define ROWU 720        // ushorts per row (30*24), 1440 B
#define HFRAG 14
#define HOFF 112        // h k-offset in weight layout (224 cols)

// ---------------------------------------------------------------- diag / zero
__global__ void diag_kernel(float* out, float val) {
    int n = blockIdx.x * 256 + threadIdx.x;
    if (n < Nn) out[n] = (n == 0) ? val : 0.f;
}
__global__ void zero_ints(int* p, int n) {
    int i = blockIdx.x * 256 + threadIdx.x;
    if (i < n) p[i] = 0;
}
// zero the 120 pad ushorts of each row (ws is poisoned every launch)
__global__ void zero_pads(ushort_t* Act) {
    int gid = blockIdx.x * 256 + threadIdx.x;     // N*120
    int n = gid / 120, p = gid - n * 120;
    int off;
    if (p < 12) {                    // frag 12, j=4..7, 3 limbs
        int limb = p >> 2, j = p & 3;
        off = 12 * 24 + limb * 8 + 4 + j;
    } else if (p < 24) {             // frag 26, j=4..7, 3 limbs
        int pp = p - 12;
        int limb = pp >> 2, j = pp & 3;
        off = 26 * 24 + limb * 8 + 4 + j;
    } else {                         // frag 13 (24) + frags 27..29 (72)
        int q2 = p - 24;
        off = (q2 < 24) ? (13 * 24 + q2) : (27 * 24 + (q2 - 24));
    }
    Act[(size_t)n * ROWU + off] = 0;
}

// ---------------------------------------------------------------- CSR build
__global__ void hist_kernel(const int* __restrict__ er, const int* __restrict__ ec,
                            int* __restrict__ cnt_f, int* __restrict__ cnt_b) {
    int e = blockIdx.x * 256 + threadIdx.x;
    atomicAdd(&cnt_f[er[e]], 1);
    atomicAdd(&cnt_b[ec[e]], 1);
}

__global__ __launch_bounds__(1024) void scan_kernel(const int* __restrict__ cnt,
                                                    int* __restrict__ ptr, int n) {
    __shared__ int sums[1024];
    int t = threadIdx.x;
    int chunk = n >> 10;
    int base = t * chunk;
    int s = 0;
    for (int i = 0; i < chunk; i++) s += cnt[base + i];
    sums[t] = s;
    __syncthreads();
    for (int off = 1; off < 1024; off <<= 1) {
        int v = (t >= off) ? sums[t - off] : 0;
        __syncthreads();
        sums[t] += v;
        __syncthreads();
    }
    int run = (t == 0) ? 0 : sums[t - 1];
    for (int i = 0; i < chunk; i++) { ptr[base + i] = run; run += cnt[base + i]; }
    if (t == 1023) ptr[n] = run;
}

// fill advances ptr in place; afterwards start(r) = (r ? ptr[r-1] : 0), end(r) = ptr[r]
__global__ void fill_kernel(const int* __restrict__ er, const int* __restrict__ ec,
                            int* __restrict__ ptr_f, int* __restrict__ ptr_b,
                            int* __restrict__ src_f, int* __restrict__ src_b) {
    int e = blockIdx.x * 256 + threadIdx.x;
    int r = er[e], c = ec[e];
    int p = atomicAdd(&ptr_f[r], 1); src_f[p] = c;
    int q = atomicAdd(&ptr_b[c], 1); src_b[q] = r;
}

// ---------------------------------------------------------------- weight prep
// GRU: Wt[c=4d+g][k], c<448 (28 tiles); k<100: Wih, 112<=k<212: Whh, else 0.
__global__ void prep_gru_w(const float* __restrict__ Wih, const float* __restrict__ Whh,
                           const float* __restrict__ bih, const float* __restrict__ bhh,
                           ushort_t* __restrict__ W0, ushort_t* __restrict__ W1,
                           ushort_t* __restrict__ W2, float* __restrict__ bg) {
    int gid = blockIdx.x * 256 + threadIdx.x;
    if (gid >= 448 * 224) return;
    int c = gid / 224, k = gid - c * 224;
    int d = c >> 2, g = c & 3;
    float w = 0.f;
    if (d < 100) {
        if (k < 100) {
            if (g == 0)      w = Wih[d * 100 + k];
            else if (g == 1) w = Wih[(100 + d) * 100 + k];
            else if (g == 2) w = Wih[(200 + d) * 100 + k];
        } else if (k >= HOFF && k < HOFF + 100) {
            int kk = k - HOFF;
            if (g == 0)      w = Whh[d * 100 + kk];
            else if (g == 1) w = Whh[(100 + d) * 100 + kk];
            else if (g == 3) w = Whh[(200 + d) * 100 + kk];
        }
    }
    uint32 h, m, l; split3(w, h, m, l);
    W0[gid] = (ushort_t)h; W1[gid] = (ushort_t)m; W2[gid] = (ushort_t)l;
    if (k == 0) {
        float b = 0.f;
        if (d < 100) {
            if (g == 0)      b = bih[d] + bhh[d];
            else if (g == 1) b = bih[100 + d] + bhh[100 + d];
            else if (g == 2) b = bih[200 + d];
            else             b = bhh[200 + d];
        }
        bg[c] = b;
    }
}

// msg MLP: W1t[c<64][k<128] (c=hidden col, k=h dim), W2t[c<112][k<64]
__global__ void prep_msg_w(const float* __restrict__ W1, const float* __restrict__ b1,
                           const float* __restrict__ W2, const float* __restrict__ b2,
                           ushort_t* __restrict__ A0, ushort_t* __restrict__ A1,
                           ushort_t* __restrict__ A2, float* __restrict__ b1p,
                           ushort_t* __restrict__ B0, ushort_t* __restrict__ B1,
                           ushort_t* __restrict__ B2, float* __restrict__ b2p) {
    int gid = blockIdx.x * 256 + threadIdx.x;
    if (gid < 8192) {
        int c = gid >> 7, k = gid & 127;
        float w = (c < 50 && k < 100) ? W1[k * 50 + c] : 0.f;
        uint32 h, m, l; split3(w, h, m, l);
        A0[gid] = (ushort_t)h; A1[gid] = (ushort_t)m; A2[gid] = (ushort_t)l;
        if (k == 0) b1p[c] = (c < 50) ? b1[c] : 0.f;
    } else if (gid < 8192 + 7168) {
        int t = gid - 8192;
        int c = t >> 6, k = t & 63;
        float w = (c < 100 && k < 50) ? W2[k * 100 + c] : 0.f;
        uint32 h, m, l; split3(w, h, m, l);
        B0[t] = (ushort_t)h; B1[t] = (ushort_t)m; B2[t] = (ushort_t)l;
        if (k == 0) b2p[c] = (c < 100) ? b2[c] : 0.f;
    }
}

// ---------------------------------------------------------------- init h
__global__ void init_h_kernel(const float* __restrict__ feat, const float* __restrict__ W,
                              const float* __restrict__ b, ushort_t* __restrict__ Act) {
    int gid = blockIdx.x * 256 + threadIdx.x;   // N*100
    int n = gid / 100, d = gid - n * 100;
    float acc = b[d];
#pragma unroll
    for (int k = 0; k < 4; k++) acc += feat[n * 4 + k] * W[k * 100 + d];
    uint32 h, m, l; split3(acc, h, m, l);
    size_t idx = (size_t)n * ROWU + (HFRAG + (d >> 3)) * 24 + (d & 7);
    Act[idx] = (ushort_t)h; Act[idx + 8] = (ushort_t)m; Act[idx + 16] = (ushort_t)l;
}

// ---------------------------------------------------------------- msg MLP (MFMA)
// fm = relu(h @ W1 + b1) @ W2 + b2 ; h read from interleaved limb fragments.
__global__ __launch_bounds__(256, 2) void msg_mfma(
    const ushort_t* __restrict__ Act,
    const ushort_t* __restrict__ A0, const ushort_t* __restrict__ A1,
    const ushort_t* __restrict__ A2, const float* __restrict__ b1p,
    const ushort_t* __restrict__ B0, const ushort_t* __restrict__ B1,
    const ushort_t* __restrict__ B2, const float* __restrict__ b2p,
    float* __restrict__ fm) {
    __shared__ ushort_t C1[3][64][72];
    const int tid = threadIdx.x;
    const int u = tid >> 6;          // wave = node tile
    const int lane = tid & 63;
    const int m = lane & 15, q = lane >> 4;
    const int n0 = blockIdx.x * 64;
    const int n = n0 + u * 16 + m;

    f32x4 z = {0.f, 0.f, 0.f, 0.f};
    f32x4 a1[4] = {z, z, z, z};

    for (int kc = 0; kc < 4; kc++) {
        size_t base = (size_t)n * ROWU + (size_t)(HFRAG + kc * 4 + q) * 24;
        short8 f0 = *(const short8*)(Act + base);
        short8 f1 = *(const short8*)(Act + base + 8);
        short8 f2 = *(const short8*)(Act + base + 16);
#pragma unroll
        for (int t = 0; t < 4; t++) {
            int off = (t * 16 + m) * 128 + kc * 32 + q * 8;
            short8 w0 = *(const short8*)(A0 + off);
            short8 w1 = *(const short8*)(A1 + off);
            short8 w2 = *(const short8*)(A2 + off);
            a1[t] = mfma16(w0, f0, a1[t]);
            a1[t] = mfma16(w0, f1, a1[t]);
            a1[t] = mfma16(w1, f0, a1[t]);
            a1[t] = mfma16(w0, f2, a1[t]);
            a1[t] = mfma16(w2, f0, a1[t]);
            a1[t] = mfma16(w1, f1, a1[t]);
        }
    }
    // epilogue 1: relu + split -> LDS
#pragma unroll
    for (int t = 0; t < 4; t++) {
        int c0 = t * 16 + 4 * q;
        float4 bb = *(const float4*)&b1p[c0];
        float v0 = fmaxf(a1[t][0] + bb.x, 0.f);
        float v1 = fmaxf(a1[t][1] + bb.y, 0.f);
        float v2 = fmaxf(a1[t][2] + bb.z, 0.f);
        float v3 = fmaxf(a1[t][3] + bb.w, 0.f);
        uint32 h0, m0, l0, h1, m1, l1, h2, m2, l2, h3, m3, l3;
        split3(v0, h0, m0, l0); split3(v1, h1, m1, l1);
        split3(v2, h2, m2, l2); split3(v3, h3, m3, l3);
        int nl = u * 16 + m;
        *(uint2*)&C1[0][nl][c0] = make_uint2(h0 | (h1 << 16), h2 | (h3 << 16));
        *(uint2*)&C1[1][nl][c0] = make_uint2(m0 | (m1 << 16), m2 | (m3 << 16));
        *(uint2*)&C1[2][nl][c0] = make_uint2(l0 | (l1 << 16), l2 | (l3 << 16));
    }
    __syncthreads();

    f32x4 a2[7] = {z, z, z, z, z, z, z};
    for (int kc = 0; kc < 2; kc++) {
        int nl = u * 16 + m;
        short8 c0f = *(const short8*)&C1[0][nl][kc * 32 + q * 8];
        short8 c1f = *(const short8*)&C1[1][nl][kc * 32 + q * 8];
        short8 c2f = *(const short8*)&C1[2][nl][kc * 32 + q * 8];
#pragma unroll
        for (int t = 0; t < 7; t++) {
            int off = (t * 16 + m) * 64 + kc * 32 + q * 8;
            short8 w0 = *(const short8*)(B0 + off);
            short8 w1 = *(const short8*)(B1 + off);
            short8 w2 = *(const short8*)(B2 + off);
            a2[t] = mfma16(w0, c0f, a2[t]);
            a2[t] = mfma16(w0, c1f, a2[t]);
            a2[t] = mfma16(w1, c0f, a2[t]);
            a2[t] = mfma16(w0, c2f, a2[t]);
            a2[t] = mfma16(w2, c0f, a2[t]);
            a2[t] = mfma16(w1, c1f, a2[t]);
        }
    }
#pragma unroll
    for (int t = 0; t < 7; t++) {
        int c0 = t * 16 + 4 * q;
        if (c0 < 100) {
            float4 bb = *(const float4*)&b2p[c0];
            float4 o;
            o.x = a2[t][0] + bb.x; o.y = a2[t][1] + bb.y;
            o.z = a2[t][2] + bb.z; o.w = a2[t][3] + bb.w;
            *(float4*)&fm[(size_t)n * 100 + c0] = o;
        }
    }
}

// ---------------------------------------------------------------- gather (CSR)
// sum in fp32, split once, write interleaved msg limbs
__global__ void gather4(const float* __restrict__ fm, const int* __restrict__ ptr,
                        const int* __restrict__ idx, ushort_t* __restrict__ Act) {
    int gid = blockIdx.x * 256 + threadIdx.x;   // N*25
    int n = gid / 25, qq = (gid - n * 25) * 4;
    int s = (n == 0) ? 0 : ptr[n - 1];
    int e = ptr[n];
    float4 acc = {0.f, 0.f, 0.f, 0.f};
    for (int i = s; i < e; i++) {
        float4 v = *(const float4*)&fm[(size_t)idx[i] * 100 + qq];
        acc.x += v.x; acc.y += v.y; acc.z += v.z; acc.w += v.w;
    }
    uint32 h0, m0, l0, h1, m1, l1, h2, m2, l2, h3, m3, l3;
    split3(acc.x, h0, m0, l0); split3(acc.y, h1, m1, l1);
    split3(acc.z, h2, m2, l2); split3(acc.w, h3, m3, l3);
    size_t base = (size_t)n * ROWU + (qq >> 3) * 24 + (qq & 7);
    *(uint2*)&Act[base]      = make_uint2(h0 | (h1 << 16), h2 | (h3 << 16));
    *(uint2*)&Act[base + 8]  = make_uint2(m0 | (m1 << 16), m2 | (m3 << 16));
    *(uint2*)&Act[base + 16] = make_uint2(l0 | (l1 << 16), l2 | (l3 << 16));
}

// ---------------------------------------------------------------- GRU (MFMA) v6
// 64-row blocks, 28 col-tiles, 7 tiles/wave (ct = 4t+wave). No LDS. Activations
// read as interleaved pre-split limb fragments (48 B contiguous per frag, zero
// split VALU in the k-loop). Product-major passes: MFMA dep distance 28.
// One barrier before the in-place h update.
__global__ __launch_bounds__(256, 2) void gru_mfma(
    ushort_t* __restrict__ Act,
    const ushort_t* __restrict__ W0, const ushort_t* __restrict__ W1,
    const ushort_t* __restrict__ W2, const float* __restrict__ bg) {
    const int tid = threadIdx.x;
    const int wave = tid >> 6;
    const int lane = tid & 63;
    const int m = lane & 15, q = lane >> 4;
    const int n0 = blockIdx.x * 64;

    f32x4 z = {0.f, 0.f, 0.f, 0.f};
    f32x4 acc[7][4];
#pragma unroll
    for (int t = 0; t < 7; t++)
#pragma unroll
        for (int rf = 0; rf < 4; rf++) acc[t][rf] = z;

    int woff[7];
#pragma unroll
    for (int t = 0; t < 7; t++)
        woff[t] = ((t * 4 + wave) * 16 + m) * 224 + q * 8;

    const size_t arow = (size_t)(n0 + m) * ROWU + (size_t)q * 24;

#define GPASS(Wreg, Fr)                                          \
    _Pragma("unroll")                                            \
    for (int t = 0; t < 7; t++) {                                \
        _Pragma("unroll")                                        \
        for (int rf = 0; rf < 4; rf++)                           \
            acc[t][rf] = mfma16(Wreg[t], Fr[rf], acc[t][rf]);    \
    }

    for (int kc = 0; kc < 7; kc++) {
        const int ko = kc * 32;
        short8 f0[4], f1[4], f2[4];
#pragma unroll
        for (int rf = 0; rf < 4; rf++) {
            size_t b = arow + (size_t)rf * 16 * ROWU + (size_t)kc * 96;
            f0[rf] = *(const short8*)(Act + b);
            f1[rf] = *(const short8*)(Act + b + 8);
            f2[rf] = *(const short8*)(Act + b + 16);
        }
        short8 w[7];
#pragma unroll
        for (int t = 0; t < 7; t++) w[t] = *(const short8*)(W0 + woff[t] + ko);
        GPASS(w, f0);                       // w0*f0
        GPASS(w, f1);                       // w0*f1
        GPASS(w, f2);                       // w0*f2
#pragma unroll
        for (int t = 0; t < 7; t++) w[t] = *(const short8*)(W1 + woff[t] + ko);
        GPASS(w, f0);                       // w1*f0
        GPASS(w, f1);                       // w1*f1
#pragma unroll
        for (int t = 0; t < 7; t++) w[t] = *(const short8*)(W2 + woff[t] + ko);
        GPASS(w, f0);                       // w2*f0
    }
#undef GPASS

    __syncthreads();    // all reads of h limbs complete before in-place overwrite

    // epilogue: gates, h update, re-split into interleaved limbs
#pragma unroll
    for (int t = 0; t < 7; t++) {
        const int ct = t * 4 + wave;        // 0..27
        const int d = ct * 4 + q;           // 0..111
        if (d < 100) {
            float4 b4 = *(const float4*)&bg[ct * 16 + 4 * q];
#pragma unroll
            for (int rf = 0; rf < 4; rf++) {
                int n = n0 + rf * 16 + m;
                size_t idx = (size_t)n * ROWU + (HFRAG + (d >> 3)) * 24 + (d & 7);
                float hold = recon3(Act[idx], Act[idx + 8], Act[idx + 16]);
                float rp = acc[t][rf][0] + b4.x;
                float zp = acc[t][rf][1] + b4.y;
                float np = acc[t][rf][2] + b4.z;
                float hh = acc[t][rf][3] + b4.w;
                float rr = 1.f / (1.f + __expf(-rp));
                float zz = 1.f / (1.f + __expf(-zp));
                float nw = tanhf(np + rr * hh);
                float hnew = (1.f - zz) * nw + zz * hold;
                uint32 h, mm, l; split3(hnew, h, mm, l);
                Act[idx] = (ushort_t)h; Act[idx + 8] = (ushort_t)mm;
                Act[idx + 16] = (ushort_t)l;
            }
        }
    }
}

// ---------------------------------------------------------------- classifier
__global__ __launch_bounds__(256) void classifier(
    const ushort_t* __restrict__ Act, const float* __restrict__ W1,
    const float* __restrict__ b1, const float* __restrict__ W2,
    const float* __restrict__ b2, float* __restrict__ out) {
    __shared__ float Wc[3000];
    __shared__ float bc[30];
    __shared__ float w2[30];
    int tid = threadIdx.x;
    for (int i = tid; i < 3000; i += 256) Wc[i] = W1[i];
    if (tid < 30) { bc[tid] = b1[tid]; w2[tid] = W2[tid]; }
    __syncthreads();
    int n = blockIdx.x * 256 + tid;
    float a[30];
#pragma unroll
    for (int j = 0; j < 30; j++) a[j] = bc[j];
    for (int k = 0; k < 100; k++) {
        size_t idx = (size_t)n * ROWU + (HFRAG + (k >> 3)) * 24 + (k & 7);
        float hv = recon3(Act[idx], Act[idx + 8], Act[idx + 16]);
#pragma unroll
        for (int j = 0; j < 30; j++) a[j] = fmaf(hv, Wc[k * 30 + j], a[j]);
    }
    float s = b2[0];
#pragma unroll
    for (int j = 0; j < 30; j++) s = fmaf(fmaxf(a[j], 0.f), w2[j], s);
    out[n] = s;
}

// ---------------------------------------------------------------- launch
extern "C" void kernel_launch(void* const* d_in, const int* in_sizes, int n_in,
                              void* d_out, int out_size, void* d_ws, size_t ws_size,
                              hipStream_t stream) {
    const float* feat     = (const float*)d_in[0];
    const int*   er       = (const int*)d_in[1];
    const int*   ec       = (const int*)d_in[2];
    const float* init_W   = (const float*)d_in[3];
    const float* init_b   = (const float*)d_in[4];
    const float* fmsg_W1  = (const float*)d_in[5];
    const float* fmsg_b1  = (const float*)d_in[6];
    const float* fmsg_W2  = (const float*)d_in[7];
    const float* fmsg_b2  = (const float*)d_in[8];
    const float* bmsg_W1  = (const float*)d_in[9];
    const float* bmsg_b1  = (const float*)d_in[10];
    const float* bmsg_W2  = (const float*)d_in[11];
    const float* bmsg_b2  = (const float*)d_in[12];
    const float* fgru_Wih = (const float*)d_in[13];
    const float* fgru_Whh = (const float*)d_in[14];
    const float* fgru_bih = (const float*)d_in[15];
    const float* fgru_bhh = (const float*)d_in[16];
    const float* bgru_Wih = (const float*)d_in[17];
    const float* bgru_Whh = (const float*)d_in[18];
    const float* bgru_bih = (const float*)d_in[19];
    const float* bgru_bhh = (const float*)d_in[20];
    const float* cls_W1   = (const float*)d_in[21];
    const float* cls_b1   = (const float*)d_in[22];
    const float* cls_W2   = (const float*)d_in[23];
    const float* cls_b2   = (const float*)d_in[24];
    float* out = (float*)d_out;

    char* base = (char*)d_ws;
    size_t off = 0;
    auto alloc = [&](size_t bytes) -> void* {
        void* p = base + off;
        off += (bytes + 15) & ~(size_t)15;
        return p;
    };

    ushort_t* Act = (ushort_t*)alloc((size_t)Nn * ROWU * 2);
    float*    fm  = (float*)alloc((size_t)Nn * 100 * 4);

    ushort_t* fWg0 = (ushort_t*)alloc(448 * 224 * 2);
    ushort_t* fWg1 = (ushort_t*)alloc(448 * 224 * 2);
    ushort_t* fWg2 = (ushort_t*)alloc(448 * 224 * 2);
    ushort_t* bWg0 = (ushort_t*)alloc(448 * 224 * 2);
    ushort_t* bWg1 = (ushort_t*)alloc(448 * 224 * 2);
    ushort_t* bWg2 = (ushort_t*)alloc(448 * 224 * 2);
    ushort_t* fA0  = (ushort_t*)alloc(8192 * 2);
    ushort_t* fA1  = (ushort_t*)alloc(8192 * 2);
    ushort_t* fA2  = (ushort_t*)alloc(8192 * 2);
    ushort_t* bA0  = (ushort_t*)alloc(8192 * 2);
    ushort_t* bA1  = (ushort_t*)alloc(8192 * 2);
    ushort_t* bA2  = (ushort_t*)alloc(8192 * 2);
    ushort_t* fB0  = (ushort_t*)alloc(7168 * 2);
    ushort_t* fB1  = (ushort_t*)alloc(7168 * 2);
    ushort_t* fB2  = (ushort_t*)alloc(7168 * 2);
    ushort_t* bB0  = (ushort_t*)alloc(7168 * 2);
    ushort_t* bB1  = (ushort_t*)alloc(7168 * 2);
    ushort_t* bB2  = (ushort_t*)alloc(7168 * 2);

    float* bgf  = (float*)alloc(448 * 4);
    float* bgb  = (float*)alloc(448 * 4);
    float* b1pf = (float*)alloc(64 * 4);
    float* b1pb = (float*)alloc(64 * 4);
    float* b2pf = (float*)alloc(112 * 4);
    float* b2pb = (float*)alloc(112 * 4);

    int* ptr_f = (int*)alloc((Nn + 1) * 4);
    int* ptr_b = (int*)alloc((Nn + 1) * 4);
    int* cnt   = (int*)alloc(2 * (size_t)Nn * 4);
    int* cnt_f = cnt;
    int* cnt_b = cnt + Nn;
    int* src_f = (int*)alloc((size_t)Ee * 4);
    int* src_b = (int*)alloc((size_t)Ee * 4);

    if (ws_size < off) {
        // diagnostic: absmax will report ~ws_size
        diag_kernel<<<(Nn + 255) / 256, 256, 0, stream>>>(out, (float)ws_size);
        return;
    }

    // CSR build
    zero_ints<<<(2 * Nn + 255) / 256, 256, 0, stream>>>(cnt, 2 * Nn);
    hist_kernel<<<Ee / 256, 256, 0, stream>>>(er, ec, cnt_f, cnt_b);
    scan_kernel<<<1, 1024, 0, stream>>>(cnt_f, ptr_f, Nn);
    scan_kernel<<<1, 1024, 0, stream>>>(cnt_b, ptr_b, Nn);
    fill_kernel<<<Ee / 256, 256, 0, stream>>>(er, ec, ptr_f, ptr_b, src_f, src_b);

    // weight prep (split to 3 bf16 limbs)
    prep_gru_w<<<(448 * 224 + 255) / 256, 256, 0, stream>>>(
        fgru_Wih, fgru_Whh, fgru_bih, fgru_bhh, fWg0, fWg1, fWg2, bgf);
    prep_gru_w<<<(448 * 224 + 255) / 256, 256, 0, stream>>>(
        bgru_Wih, bgru_Whh, bgru_bih, bgru_bhh, bWg0, bWg1, bWg2, bgb);
    prep_msg_w<<<(15360 + 255) / 256, 256, 0, stream>>>(
        fmsg_W1, fmsg_b1, fmsg_W2, fmsg_b2, fA0, fA1, fA2, b1pf, fB0, fB1, fB2, b2pf);
    prep_msg_w<<<(15360 + 255) / 256, 256, 0, stream>>>(
        bmsg_W1, bmsg_b1, bmsg_W2, bmsg_b2, bA0, bA1, bA2, b1pb, bB0, bB1, bB2, b2pb);

    // activation pads + h init (split into interleaved limbs)
    zero_pads<<<(Nn * 120) / 256, 256, 0, stream>>>(Act);
    init_h_kernel<<<(Nn * 100) / 256, 256, 0, stream>>>(feat, init_W, init_b, Act);

    const int gTile = Nn / 64;            // 2048 (msg, gru)
    const int gGath = Nn * 25 / 256;      // 12800

    for (int rd = 0; rd < 20; rd++) {
        msg_mfma<<<gTile, 256, 0, stream>>>(Act, fA0, fA1, fA2, b1pf,
                                            fB0, fB1, fB2, b2pf, fm);
        gather4<<<gGath, 256, 0, stream>>>(fm, ptr_f, src_f, Act);
        gru_mfma<<<gTile, 256, 0, stream>>>(Act, fWg0, fWg1, fWg2, bgf);

        msg_mfma<<<gTile, 256, 0, stream>>>(Act, bA0, bA1, bA2, b1pb,
                                            bB0, bB1, bB2, b2pb, fm);
        gather4<<<gGath, 256, 0, stream>>>(fm, ptr_b, src_b, Act);
        gru_mfma<<<gTile, 256, 0, stream>>>(Act, bWg0, bWg1, bWg2, bgb);
    }

    classifier<<<Nn / 256, 256, 0, stream>>>(Act, cls_W1, cls_b1,
                                             cls_W2, cls_b2, out);
}